// Round 2
// baseline (435.149 us; speedup 1.0000x reference)
//
#include <hip/hip_runtime.h>

#define LAMBDA_COORD 5.0f
#define LAMBDA_NOOBJ 0.5f

constexpr int NC = 30;                 // channels per cell
constexpr int CPB = 128;               // cells per block (= blockDim.x)
constexpr int NFLOAT = CPB * NC;       // 3840 floats per array per block
constexpr int NVEC4 = NFLOAT / 4;      // 960 float4 per array
constexpr int TOTV4 = 2 * NVEC4;       // 1920 staged float4 (pred then targ)
constexpr int LOADS = TOTV4 / CPB;     // 15 float4 loads per thread

__global__ void zero_out_kernel(float* out) { out[0] = 0.0f; }

__global__ __launch_bounds__(CPB) void yolo_loss_kernel(
    const float* __restrict__ pred,
    const float* __restrict__ targ,
    float* __restrict__ out)
{
    // LDS slab: first NVEC4 float4 = pred cells, next NVEC4 = targ cells.
    __shared__ float4 s[TOTV4];   // 30720 B -> 5 blocks/CU

    const int tid = threadIdx.x;
    const size_t base = (size_t)blockIdx.x * NFLOAT;
    const float4* p4 = (const float4*)(pred + base);
    const float4* t4 = (const float4*)(targ + base);

    // Issue ALL global loads before any use: 15 independent dwordx4 per
    // thread, fully coalesced (lane i -> base + i*16B).
    float4 r[LOADS];
#pragma unroll
    for (int k = 0; k < LOADS; ++k) {
        int j = tid + k * CPB;
        const float4* src = (j < NVEC4) ? (p4 + j) : (t4 + (j - NVEC4));
        r[k] = *src;
    }
#pragma unroll
    for (int k = 0; k < LOADS; ++k) {
        s[tid + k * CPB] = r[k];
    }
    __syncthreads();

    // Per-cell compute out of LDS. Cell record is 30 floats, 8B-aligned
    // (120 B) -> float2 reads (ds_read_b64). Stride-30 gives 4-way bank
    // conflicts (1.58x LDS cost) -- under the HBM budget.
    const float* spf = (const float*)s;          // pred floats
    const float* stf = spf + NFLOAT;             // targ floats
    const float2* pp = (const float2*)(spf + tid * NC);
    const float2* tt = (const float2*)(stf + tid * NC);

    float p[NC], t[NC];
#pragma unroll
    for (int i = 0; i < NC / 2; ++i) {
        float2 a = pp[i]; p[2 * i] = a.x; p[2 * i + 1] = a.y;
        float2 b = tt[i]; t[2 * i] = b.x; t[2 * i + 1] = b.y;
    }

    float obj   = (t[4] > 0.0f)  ? 1.0f : 0.0f;
    float noobj = (t[4] == 0.0f) ? 1.0f : 0.0f;

    // IoU of both pred boxes vs target box. Division only feeds a compare:
    // fast divide is fine (flips only exact near-ties).
    float ltx0 = fmaxf(p[0], t[0]), lty0 = fmaxf(p[1], t[1]);
    float rbx0 = fminf(p[2], t[2]), rby0 = fminf(p[3], t[3]);
    float inter0 = fmaxf(rbx0 - ltx0, 0.0f) * fmaxf(rby0 - lty0, 0.0f);
    float a10 = (p[2] - p[0]) * (p[3] - p[1]);

    float ltx1 = fmaxf(p[5], t[0]), lty1 = fmaxf(p[6], t[1]);
    float rbx1 = fminf(p[7], t[2]), rby1 = fminf(p[8], t[3]);
    float inter1 = fmaxf(rbx1 - ltx1, 0.0f) * fmaxf(rby1 - lty1, 0.0f);
    float a11 = (p[7] - p[5]) * (p[8] - p[6]);

    float a2 = (t[2] - t[0]) * (t[3] - t[1]);
    float iou0 = __fdividef(inter0, a10 + a2 - inter0);
    float iou1 = __fdividef(inter1, a11 + a2 - inter1);
    bool c0 = (iou0 >= iou1);   // argmax ties -> box 0

    int o = c0 ? 0 : 5;
    float dx = p[o + 0] - t[o + 0];
    float dy = p[o + 1] - t[o + 1];
    float l1 = dx * dx + dy * dy;
    float sw = sqrtf(p[o + 2]) - sqrtf(t[o + 2]);
    float sh = sqrtf(p[o + 3]) - sqrtf(t[o + 3]);
    float l2 = sw * sw + sh * sh;
    float dc = p[o + 4] - t[o + 4];
    float conf = dc * dc;

    float cls = 0.0f;
#pragma unroll
    for (int c = 10; c < NC; ++c) {
        float d = p[c] - t[c];
        cls += d * d;
    }

    float loss = LAMBDA_COORD * (l1 + l2) * obj
               + conf * obj
               + LAMBDA_NOOBJ * conf * noobj
               + cls * obj;

    // Wave-64 butterfly, then cross-wave (2 waves) via LDS, one atomic/block.
#pragma unroll
    for (int off = 32; off > 0; off >>= 1)
        loss += __shfl_down(loss, off, 64);

    __shared__ float wsum[CPB / 64];
    int lane = tid & 63;
    int wid  = tid >> 6;
    if (lane == 0) wsum[wid] = loss;
    __syncthreads();
    if (tid == 0) {
        float ssum = 0.0f;
#pragma unroll
        for (int w = 0; w < CPB / 64; ++w) ssum += wsum[w];
        atomicAdd(out, ssum);
    }
}

extern "C" void kernel_launch(void* const* d_in, const int* in_sizes, int n_in,
                              void* d_out, int out_size, void* d_ws, size_t ws_size,
                              hipStream_t stream) {
    const float* pred = (const float*)d_in[0];
    const float* targ = (const float*)d_in[1];
    float* out = (float*)d_out;

    int ncells = in_sizes[0] / NC;           // 2048*28*28 = 1,605,632
    int grid = ncells / CPB;                 // 12544, exact

    zero_out_kernel<<<1, 1, 0, stream>>>(out);
    yolo_loss_kernel<<<grid, CPB, 0, stream>>>(pred, targ, out);
}